// Round 8
// baseline (17517.897 us; speedup 1.0000x reference)
//
#include <hip/hip_runtime.h>
#include <hip/hip_bf16.h>

// BiLSTM-CRF on MI355X.  VOCAB=50000, EMB=256, HID=512 (H=256/dir), NTAG=20, SEQ=8192.
//
// Round-8 scan redesign (rest of pipeline identical to round 4):
//  * gate-interleaved lanes: gates (i,f,g,o) of one h in 4 adjacent lanes ->
//    act->cell via 3 __shfl_down; 2 barriers/step instead of 3.
//  * poller waves (tid 256..447) poll peers' h CONCURRENTLY with the
//    producer tail (act/cell/publish) -> LLC visibility overlaps compute.
//  * 4-slot staggered inline-asm poll ring (s_sleep-spaced issues,
//    s_waitcnt vmcnt(3) per slot): discovery granularity ~150cy vs ~RT.
//  * per-(consumer,producer,parity) private 32-bit slots holding a NaN
//    sentinel; consumer resets after read (2-step = ~4000cy margin).
//    Budgeted ring falls back to polling out[t] (unique address per step,
//    poison-checked) -> hang-impossible.
// Lesson bank: agent visibility needs sc0 AND sc1 (L1+L2 bypass); plain/sc0
// paths read stale own-XCD L2 (rounds 5/7).

#define S    8192
#define E    256
#define Hh   256          // per-direction hidden
#define G    1024         // 4*Hh gates
#define NT   20
#define NB   4            // blocks (CUs) per direction
#define NCHUNK 128        // 8192 / 64
#define CLEN   64
#define SENTU 0x7FC0DEADu // NaN pattern; h is never NaN
#define POISON 0xAAAAAAAAu

// ---------------------------------------------------------------- priv init
// priv: [dir][cons 4][prod 4][parity 2][64] f32 = 4096 words (16 KB)
__global__ __launch_bounds__(256) void priv_init(unsigned* __restrict__ p)
{
    int i = blockIdx.x * 256 + threadIdx.x;
    if (i < 4096) p[i] = SENTU;
}

// ---------------------------------------------------------------- xg projection
__global__ __launch_bounds__(1024, 4) void xg_project(
    const int* __restrict__ sent, const float* __restrict__ embed,
    const float* __restrict__ Wih_f, const float* __restrict__ bih_f, const float* __restrict__ bhh_f,
    const float* __restrict__ Wih_b, const float* __restrict__ bih_b, const float* __restrict__ bhh_b,
    float* __restrict__ xg)                       // [2][S][G]
{
    const int tb  = blockIdx.x;                   // 0..255 (32 timesteps each)
    const int rb  = blockIdx.y;                   // 0..3
    const int dir = blockIdx.z;                   // 0..1
    const int tid = threadIdx.x;
    const int q   = tid >> 8;                     // k-quarter 0..3
    const int idx = tid & 255;
    const int r   = rb * 256 + idx;               // gate row 0..1023
    const float* Wih = dir ? Wih_b : Wih_f;

    __shared__ __align__(16) float4 xs4[32 * 64]; // 32 timesteps x 256 floats (32 KB)
    __shared__ float psum[1024];

    const int t0 = tb * 32;
    #pragma unroll
    for (int i = 0; i < 2; ++i) {
        int qq  = i * 1024 + tid;                 // 2048 float4 total
        int row = qq >> 6;
        int c4  = qq & 63;
        int widx = sent[t0 + row];
        xs4[qq] = *(const float4*)(embed + (size_t)widx * E + (size_t)c4 * 4);
    }

    float w[64];
    #pragma unroll
    for (int k = 0; k < 64; k += 4) {
        float4 v = *(const float4*)(Wih + (size_t)r * E + q * 64 + k);
        w[k] = v.x; w[k+1] = v.y; w[k+2] = v.z; w[k+3] = v.w;
    }
    float bias = 0.f;
    if (tid < 256) bias = dir ? (bih_b[r] + bhh_b[r]) : (bih_f[r] + bhh_f[r]);
    __syncthreads();

    const float* xs = (const float*)xs4 + q * 64;
    float* outb = xg + ((size_t)dir * S + t0) * G + r;
    for (int tt = 0; tt < 32; ++tt) {
        float a0 = 0.f, a1 = 0.f, a2 = 0.f, a3 = 0.f;
        #pragma unroll
        for (int k = 0; k < 64; k += 4) {
            float4 h4 = *(const float4*)(xs + tt * E + k);   // LDS broadcast
            a0 = fmaf(w[k],   h4.x, a0);
            a1 = fmaf(w[k+1], h4.y, a1);
            a2 = fmaf(w[k+2], h4.z, a2);
            a3 = fmaf(w[k+3], h4.w, a3);
        }
        psum[tid] = (a0 + a1) + (a2 + a3);
        __syncthreads();
        if (tid < 256)
            outb[(size_t)tt * G] = bias +
                ((psum[idx] + psum[idx + 256]) + (psum[idx + 512] + psum[idx + 768]));
        __syncthreads();                          // psum reused next tt
    }
}

// ---------------------------------------------------------------- LSTM scan
// Grid (NB,2). Block (b,dir) owns h [b*64,b*64+64) = 256 gate rows.
// Thread (q=tid>>8, idx=tid&255): gate=idx&3, hloc=idx>>2,
// row = gate*256 + b*64 + hloc, k-range q*64..q*64+64 (w[64] in regs).
// Pollers: tid 256..447 (waves 4-6, fully active -> wave-level asm legal).
__global__ __launch_bounds__(1024, 4) void lstm_scan4(
    const float* __restrict__ xg,                 // [2][S][G]
    const float* __restrict__ Whh_f,
    const float* __restrict__ Whh_b,
    float* __restrict__ out,                      // [S][512]
    float* __restrict__ priv)                     // [2][4][4][2][64]
{
    const int b   = blockIdx.x;
    const int dir = blockIdx.y;
    const int tid = threadIdx.x;
    const int q    = tid >> 8;
    const int idx  = tid & 255;
    const int gate = idx & 3;
    const int hloc = idx >> 2;
    const int row  = gate * Hh + b * 64 + hloc;
    const float* W   = dir ? Whh_b : Whh_f;
    const float* xgd = xg + (size_t)dir * S * G;

    float w[64];
    #pragma unroll
    for (int k = 0; k < 64; k += 4) {
        float4 v = *(const float4*)(W + (size_t)row * Hh + q * 64 + k);
        w[k] = v.x; w[k+1] = v.y; w[k+2] = v.z; w[k+3] = v.w;
    }

    __shared__ __align__(16) float h_lds[Hh];
    __shared__ float psum[1024];
    if (tid < Hh) h_lds[tid] = 0.f;
    float c = 0.f;

    const bool isPoll = (tid >= 256 && tid < 448);  // waves 4..6, wave-uniform
    const int pl   = tid - 256;
    const int pi   = pl >> 6;                        // peer index 0..2 (wave-uniform)
    const int word = pl & 63;
    const int pb   = pi + (pi >= b);                 // peer block id
    const int lane = tid & 63;

    const int t0 = dir ? (S - 1) : 0;
    const int dt = dir ? -1 : 1;
    float xg_c = 0.f, xg_n1 = 0.f;                   // 2-deep prefetch
    if (tid < 256) {
        xg_c  = xgd[(size_t)t0 * G + row];
        xg_n1 = xgd[(size_t)(t0 + dt) * G + row];
    }
    unsigned g0 = 0, g1 = 0, g2 = 0, g3 = 0;         // ring ghost registers
    __syncthreads();

    for (int s = 0; s < S; ++s) {
        const int t = t0 + dt * s;
        float xg_n2 = 0.f;
        if (tid < 256 && s + 2 < S) xg_n2 = xgd[(size_t)(t + 2 * dt) * G + row];

        // partial matvec over this thread's k-quarter (wave-uniform LDS bcast)
        const float* hh = (const float*)h_lds + q * 64;
        float a0 = 0.f, a1 = 0.f, a2 = 0.f, a3 = 0.f;
        #pragma unroll
        for (int k = 0; k < 64; k += 4) {
            float4 h4 = *(const float4*)(hh + k);
            a0 = fmaf(w[k],   h4.x, a0);
            a1 = fmaf(w[k+1], h4.y, a1);
            a2 = fmaf(w[k+2], h4.z, a2);
            a3 = fmaf(w[k+3], h4.w, a3);
        }
        psum[tid] = (a0 + a1) + (a2 + a3);
        __syncthreads();                                     // B1: partials ready

        if (tid < 256) {
            // combine quarters + activation (values bit-identical to round 4)
            float acc = xg_c +
                ((psum[idx] + psum[idx + 256]) + (psum[idx + 512] + psum[idx + 768]));
            float a = (gate == 2) ? tanhf(acc) : 1.f / (1.f + expf(-acc));
            float fv = __shfl_down(a, 1);
            float gv = __shfl_down(a, 2);
            float ov = __shfl_down(a, 3);
            if (gate == 0) {                                 // cell lane (i-gate)
                c = fv * c + a * gv;
                float h = ov * tanhf(c);
                const int par = s & 1;
                #pragma unroll
                for (int ci = 0; ci < 3; ++ci) {
                    int cons = ci + (ci >= b);
                    __hip_atomic_store(
                        &priv[(((dir * 4 + cons) * 4 + b) * 2 + par) * 64 + hloc], h,
                        __ATOMIC_RELAXED, __HIP_MEMORY_SCOPE_AGENT);
                }
                __hip_atomic_store(&out[(size_t)t * 512 + dir * Hh + b * 64 + hloc],
                                   h, __ATOMIC_RELAXED, __HIP_MEMORY_SCOPE_AGENT);
                h_lds[b * 64 + hloc] = h;
            }
        } else if (isPoll && s + 1 < S) {
            // poll peer pb's word for h(s) -- runs concurrently with tail above
            const float* sp =
                &priv[(((dir * 4 + b) * 4 + pb) * 2 + (s & 1)) * 64 + word];
            unsigned res = 0, bud = 300;
            unsigned long long dn = 0, rem;
            asm volatile(
                // fast pre-check (data often already there)
                "global_load_dword %[g0], %[a], off sc0 sc1\n\t"
                "s_waitcnt vmcnt(0)\n\t"
                "v_cmp_ne_u32 vcc, 0x7fc0dead, %[g0]\n\t"
                "v_cndmask_b32 %[res], %[res], %[g0], vcc\n\t"
                "s_or_b64 %[dn], %[dn], vcc\n\t"
                "s_andn2_b64 %[rem], exec, %[dn]\n\t"
                "s_cbranch_scc0 RED%=\n\t"
                // staggered 4-slot ring (loads spaced ~128cy)
                "global_load_dword %[g0], %[a], off sc0 sc1\n\t"
                "s_sleep 2\n\t"
                "global_load_dword %[g1], %[a], off sc0 sc1\n\t"
                "s_sleep 2\n\t"
                "global_load_dword %[g2], %[a], off sc0 sc1\n\t"
                "s_sleep 2\n\t"
                "global_load_dword %[g3], %[a], off sc0 sc1\n\t"
                "RING%=:\n\t"
                "s_waitcnt vmcnt(3)\n\t"
                "v_cmp_ne_u32 vcc, 0x7fc0dead, %[g0]\n\t"
                "s_andn2_b64 vcc, vcc, %[dn]\n\t"
                "v_cndmask_b32 %[res], %[res], %[g0], vcc\n\t"
                "s_or_b64 %[dn], %[dn], vcc\n\t"
                "s_andn2_b64 %[rem], exec, %[dn]\n\t"
                "s_cbranch_scc0 RED%=\n\t"
                "global_load_dword %[g0], %[a], off sc0 sc1\n\t"
                "s_waitcnt vmcnt(3)\n\t"
                "v_cmp_ne_u32 vcc, 0x7fc0dead, %[g1]\n\t"
                "s_andn2_b64 vcc, vcc, %[dn]\n\t"
                "v_cndmask_b32 %[res], %[res], %[g1], vcc\n\t"
                "s_or_b64 %[dn], %[dn], vcc\n\t"
                "s_andn2_b64 %[rem], exec, %[dn]\n\t"
                "s_cbranch_scc0 RED%=\n\t"
                "global_load_dword %[g1], %[a], off sc0 sc1\n\t"
                "s_waitcnt vmcnt(3)\n\t"
                "v_cmp_ne_u32 vcc, 0x7fc0dead, %[g2]\n\t"
                "s_andn2_b64 vcc, vcc, %[dn]\n\t"
                "v_cndmask_b32 %[res], %[res], %[g2], vcc\n\t"
                "s_or_b64 %[dn], %[dn], vcc\n\t"
                "s_andn2_b64 %[rem], exec, %[dn]\n\t"
                "s_cbranch_scc0 RED%=\n\t"
                "global_load_dword %[g2], %[a], off sc0 sc1\n\t"
                "s_waitcnt vmcnt(3)\n\t"
                "v_cmp_ne_u32 vcc, 0x7fc0dead, %[g3]\n\t"
                "s_andn2_b64 vcc, vcc, %[dn]\n\t"
                "v_cndmask_b32 %[res], %[res], %[g3], vcc\n\t"
                "s_or_b64 %[dn], %[dn], vcc\n\t"
                "s_andn2_b64 %[rem], exec, %[dn]\n\t"
                "s_cbranch_scc0 RED%=\n\t"
                "global_load_dword %[g3], %[a], off sc0 sc1\n\t"
                "s_sub_u32 %[bud], %[bud], 1\n\t"
                "s_cmp_lg_u32 %[bud], 0\n\t"
                "s_cbranch_scc1 RING%=\n\t"
                "RED%=:\n\t"
                : [g0]"+v"(g0), [g1]"+v"(g1), [g2]"+v"(g2), [g3]"+v"(g3),
                  [res]"+v"(res), [dn]"+s"(dn), [bud]"+s"(bud), [rem]"=s"(rem)
                : [a]"v"(sp)
                : "vcc", "memory");
            if (!((dn >> lane) & 1)) {                       // budget exhausted
                const unsigned* op = (const unsigned*)
                    (out + (size_t)t * 512 + dir * Hh + pb * 64 + word);
                unsigned v;
                do {
                    v = __hip_atomic_load(op, __ATOMIC_RELAXED,
                                          __HIP_MEMORY_SCOPE_AGENT);
                } while (v == POISON);
                res = v;
            }
            h_lds[pb * 64 + word] = __uint_as_float(res);
            __hip_atomic_store((unsigned*)sp, SENTU,
                               __ATOMIC_RELAXED, __HIP_MEMORY_SCOPE_AGENT);
        }
        __syncthreads();                                     // B2: h(t) in LDS
        xg_c = xg_n1; xg_n1 = xg_n2;
    }
    asm volatile("" :: "v"(g0), "v"(g1), "v"(g2), "v"(g3)); // keep ghosts live
    asm volatile("s_waitcnt vmcnt(0)" ::: "memory");        // drain before endpgm
}

// ---------------------------------------------------------------- emissions
__global__ __launch_bounds__(256) void emissions_kernel(
    const float* __restrict__ lo,                 // [S][512]
    const float* __restrict__ Wout,               // [NT][512]
    const float* __restrict__ bout,
    float* __restrict__ em)                       // [S][NT]
{
    int gid = blockIdx.x * blockDim.x + threadIdx.x;
    if (gid >= S * NT) return;
    int t = gid / NT;
    int j = gid - t * NT;
    const float* x = lo + (size_t)t * 512;
    const float* w = Wout + (size_t)j * 512;
    float a0 = 0.f, a1 = 0.f, a2 = 0.f, a3 = 0.f;
    #pragma unroll 8
    for (int k = 0; k < 512; k += 4) {
        float4 xv = *(const float4*)(x + k);
        float4 wv = *(const float4*)(w + k);
        a0 = fmaf(xv.x, wv.x, a0);
        a1 = fmaf(xv.y, wv.y, a1);
        a2 = fmaf(xv.z, wv.z, a2);
        a3 = fmaf(xv.w, wv.w, a3);
    }
    em[gid] = bout[j] + ((a0 + a1) + (a2 + a3));
}

// ---------------------------------------------------------------- viterbi forward
// 64 lanes: lane = g*20 + j (g=0..2 active, lanes 60..63 spectators).
__global__ __launch_bounds__(64) void viterbi_fwd(
    const float* __restrict__ em,                 // [S][NT]
    const float* __restrict__ start_trans,
    const float* __restrict__ end_trans,
    const float* __restrict__ trans,              // [NT][NT] (from,to)
    unsigned char* __restrict__ bp,               // [S][NT]
    int* __restrict__ last_out)
{
    const int lane = threadIdx.x;
    const int g    = lane / 20;                   // 0,1,2 (3 = spectator)
    const int j    = lane - g * 20;               // to-tag (0..19 for g<3)
    const int i0   = g * 7;

    float tc[7];
    #pragma unroll
    for (int u = 0; u < 7; ++u) {
        int i = i0 + u;
        tc[u] = (g < 3 && i < 20) ? trans[i * NT + j] : -3.0e38f;
    }

    const int jj = (g < 3) ? j : 0;               // safe index for spectators
    float snew  = start_trans[jj] + em[jj];       // score(0)
    if (g == 0) bp[j] = (unsigned char)j;         // t=0: identity (never used)
    float e_cur = em[NT + jj];

    for (int t = 1; t < S; ++t) {
        float s_sub[7];
        #pragma unroll
        for (int u = 0; u < 7; ++u)
            s_sub[u] = __shfl(snew, i0 + u);      // sources are lanes 0..27
        float e_nxt = (t + 1 < S) ? em[(size_t)(t + 1) * NT + jj] : 0.f;

        float bv = s_sub[0] + tc[0];
        int   bi = i0;
        #pragma unroll
        for (int u = 1; u < 7; ++u) {
            float v = s_sub[u] + tc[u];
            if (v > bv) { bv = v; bi = i0 + u; }  // strict >: first-index in group
        }
        float v0 = __shfl(bv, jj), v1 = __shfl(bv, jj + 20), v2 = __shfl(bv, jj + 40);
        int   c0 = __shfl(bi, jj), c1 = __shfl(bi, jj + 20), c2 = __shfl(bi, jj + 40);
        float best = v0; int bidx = c0;
        if (v1 > best) { best = v1; bidx = c1; }
        if (v2 > best) { best = v2; bidx = c2; }
        snew = best + e_cur;
        if (g == 0) bp[(size_t)t * NT + j] = (unsigned char)bidx;
        e_cur = e_nxt;
    }

    float bv = __shfl(snew, 0) + end_trans[0];
    int   bi = 0;
    #pragma unroll 1
    for (int i = 1; i < 20; ++i) {
        float v = __shfl(snew, i) + end_trans[i];
        if (v > bv) { bv = v; bi = i; }
    }
    if (lane == 0) *last_out = bi;
}

// ---------------------------------------------------------------- backtrace
__global__ __launch_bounds__(64) void bt_maps(
    const unsigned char* __restrict__ bp, unsigned char* __restrict__ maps)
{
    __shared__ unsigned char lbp[CLEN * NT];
    const int c = blockIdx.x, tid = threadIdx.x;
    const unsigned* src = (const unsigned*)(bp + (size_t)c * CLEN * NT);
    unsigned* dst = (unsigned*)lbp;
    for (int q = tid; q < CLEN * NT / 4; q += 64) dst[q] = src[q];
    __syncthreads();
    if (tid < NT) {
        int x = tid;
        for (int t = CLEN - 1; t >= 0; --t) x = lbp[t * NT + x];
        maps[c * NT + tid] = (unsigned char)x;
    }
}

__global__ __launch_bounds__(64) void bt_boundary(
    const unsigned char* __restrict__ maps, const int* __restrict__ last_out,
    int* __restrict__ btags)
{
    __shared__ unsigned char m[NCHUNK * NT];
    const int tid = threadIdx.x;
    for (int q = tid; q < NCHUNK * NT; q += 64) m[q] = maps[q];
    __syncthreads();
    if (tid == 0) {
        int x = *last_out;
        btags[NCHUNK - 1] = x;
        for (int c = NCHUNK - 1; c >= 1; --c) {
            x = m[c * NT + x];
            btags[c - 1] = x;
        }
    }
}

__global__ __launch_bounds__(64) void bt_emit(
    const unsigned char* __restrict__ bp, const int* __restrict__ btags,
    int* __restrict__ path)
{
    __shared__ unsigned char lbp[CLEN * NT];
    const int c = blockIdx.x, tid = threadIdx.x;
    const unsigned* src = (const unsigned*)(bp + (size_t)c * CLEN * NT);
    unsigned* dst = (unsigned*)lbp;
    for (int q = tid; q < CLEN * NT / 4; q += 64) dst[q] = src[q];
    __syncthreads();
    if (tid == 0) {
        int x = btags[c];
        path[c * CLEN + CLEN - 1] = x;
        for (int t = CLEN - 1; t >= 1; --t) {
            x = lbp[t * NT + x];
            path[c * CLEN + t - 1] = x;
        }
    }
}

// ---------------------------------------------------------------- launcher
extern "C" void kernel_launch(void* const* d_in, const int* in_sizes, int n_in,
                              void* d_out, int out_size, void* d_ws, size_t ws_size,
                              hipStream_t stream) {
    const int*   sent   = (const int*)  d_in[0];
    const float* embed  = (const float*)d_in[1];
    const float* Wih_f  = (const float*)d_in[2];
    const float* Whh_f  = (const float*)d_in[3];
    const float* bih_f  = (const float*)d_in[4];
    const float* bhh_f  = (const float*)d_in[5];
    const float* Wih_b  = (const float*)d_in[6];
    const float* Whh_b  = (const float*)d_in[7];
    const float* bih_b  = (const float*)d_in[8];
    const float* bhh_b  = (const float*)d_in[9];
    const float* Wout   = (const float*)d_in[10];
    const float* bout   = (const float*)d_in[11];
    const float* start_trans = (const float*)d_in[12];
    const float* end_trans   = (const float*)d_in[13];
    const float* trans       = (const float*)d_in[14];
    int* path = (int*)d_out;

    char* ws = (char*)d_ws;
    size_t off = 0;
    float* xg = (float*)(ws + off); off += (size_t)2 * S * G * 4;   // 64 MB
    float* lo = (float*)(ws + off); off += (size_t)S * 512 * 4;     // 16 MB
    float* em = (float*)(ws + off); off += (size_t)S * NT * 4;      // 640 KB
    unsigned char* bp   = (unsigned char*)(ws + off); off += (size_t)S * NT;  // 160 KB
    unsigned char* maps = (unsigned char*)(ws + off); off += 4096;
    int* btags = (int*)(ws + off); off += 1024;
    int* lastp = (int*)(ws + off); off += 256;
    off = (off + 255) & ~(size_t)255;
    float* priv = (float*)(ws + off); off += 4096 * 4;              // 16 KB

    priv_init<<<dim3(16), 256, 0, stream>>>((unsigned*)priv);
    xg_project<<<dim3(S / 32, 4, 2), 1024, 0, stream>>>(
        sent, embed, Wih_f, bih_f, bhh_f, Wih_b, bih_b, bhh_b, xg);
    lstm_scan4<<<dim3(NB, 2), 1024, 0, stream>>>(xg, Whh_f, Whh_b, lo, priv);
    emissions_kernel<<<dim3((S * NT + 255) / 256), 256, 0, stream>>>(lo, Wout, bout, em);
    viterbi_fwd<<<dim3(1), 64, 0, stream>>>(em, start_trans, end_trans, trans, bp, lastp);
    bt_maps<<<dim3(NCHUNK), 64, 0, stream>>>(bp, maps);
    bt_boundary<<<dim3(1), 64, 0, stream>>>(maps, lastp, btags);
    bt_emit<<<dim3(NCHUNK), 64, 0, stream>>>(bp, btags, path);
}

// Round 10
// 17071.066 us; speedup vs baseline: 1.0262x; 1.0262x over previous
//
#include <hip/hip_runtime.h>
#include <hip/hip_bf16.h>

// BiLSTM-CRF on MI355X.  VOCAB=50000, EMB=256, HID=512 (H=256/dir), NTAG=20, SEQ=8192.
//
// Round-10: same-XCD L2-atomic h exchange, made hang-proof.
//  * Election (proven r5): 64 candidates read HW_REG_XCC_ID, take tickets;
//    first XCD to collect 8 blocks wins; its 8 blocks are the workers.
//  * Handshake tests the exact RMW pair (wg-scope exch / wg-scope add0),
//    bounded spins; vote via ONE atomic word (arrival|ok counts packed) --
//    round 9 deadlocked on a two-word relaxed vote (mixed fast/slow modes).
//  * Producer ALWAYS dual-publishes: wg-scope atomicExch into the L2 slot
//    AND fire-and-forget agent-scope store into the LLC slot. Consumers in
//    fast mode poll the L2 slot with a 256-RMW budget, then sticky-downgrade
//    to the proven agent/LLC poll. Every new spin loop is bounded.
//  * Stamped parity-double-buffered slots (lockstep induction => no
//    overwrite); cleared each launch -> graph-replay safe.
// Compute core = round 8 (gate-interleaved shfl combine, 2 barriers/step,
// poller waves 256..447 overlap producer tail, 2-deep xg prefetch).

#define S    8192
#define E    256
#define Hh   256          // per-direction hidden
#define G    1024         // 4*Hh gates
#define NT   20
#define NB   4            // blocks (CUs) per direction
#define NCAND 64          // candidate blocks for XCD election
#define NCHUNK 128        // 8192 / 64
#define CLEN   64
#define HSMAGIC 0xBEEF0000ull

__device__ __forceinline__ int get_xcc_id() {
    int x;
    asm volatile("s_getreg_b32 %0, hwreg(HW_REG_XCC_ID)" : "=s"(x));
    return x & 0xf;
}

// ---------------------------------------------------------------- sync init
// fslot/sslot: u64[2][2][4][64] = 1024 u64 each. hs: u64[8].
// ctl: int[18] = cnt[16], winner, votes.
__global__ __launch_bounds__(1024) void init_sync(
    unsigned long long* __restrict__ fslot, unsigned long long* __restrict__ sslot,
    unsigned long long* __restrict__ hs, int* __restrict__ ctl)
{
    int i = threadIdx.x;
    fslot[i] = 0ull;
    sslot[i] = 0ull;
    if (i < 8)  hs[i] = 0ull;
    if (i < 16) ctl[i] = 0;
    if (i == 0) { ctl[16] = -1; ctl[17] = 0; }
}

// ---------------------------------------------------------------- xg projection
__global__ __launch_bounds__(1024, 4) void xg_project(
    const int* __restrict__ sent, const float* __restrict__ embed,
    const float* __restrict__ Wih_f, const float* __restrict__ bih_f, const float* __restrict__ bhh_f,
    const float* __restrict__ Wih_b, const float* __restrict__ bih_b, const float* __restrict__ bhh_b,
    float* __restrict__ xg)                       // [2][S][G]
{
    const int tb  = blockIdx.x;                   // 0..255 (32 timesteps each)
    const int rb  = blockIdx.y;                   // 0..3
    const int dir = blockIdx.z;                   // 0..1
    const int tid = threadIdx.x;
    const int q   = tid >> 8;                     // k-quarter 0..3
    const int idx = tid & 255;
    const int r   = rb * 256 + idx;               // gate row 0..1023
    const float* Wih = dir ? Wih_b : Wih_f;

    __shared__ __align__(16) float4 xs4[32 * 64]; // 32 timesteps x 256 floats (32 KB)
    __shared__ float psum[1024];

    const int t0 = tb * 32;
    #pragma unroll
    for (int i = 0; i < 2; ++i) {
        int qq  = i * 1024 + tid;                 // 2048 float4 total
        int row = qq >> 6;
        int c4  = qq & 63;
        int widx = sent[t0 + row];
        xs4[qq] = *(const float4*)(embed + (size_t)widx * E + (size_t)c4 * 4);
    }

    float w[64];
    #pragma unroll
    for (int k = 0; k < 64; k += 4) {
        float4 v = *(const float4*)(Wih + (size_t)r * E + q * 64 + k);
        w[k] = v.x; w[k+1] = v.y; w[k+2] = v.z; w[k+3] = v.w;
    }
    float bias = 0.f;
    if (tid < 256) bias = dir ? (bih_b[r] + bhh_b[r]) : (bih_f[r] + bhh_f[r]);
    __syncthreads();

    const float* xs = (const float*)xs4 + q * 64;
    float* outb = xg + ((size_t)dir * S + t0) * G + r;
    for (int tt = 0; tt < 32; ++tt) {
        float a0 = 0.f, a1 = 0.f, a2 = 0.f, a3 = 0.f;
        #pragma unroll
        for (int k = 0; k < 64; k += 4) {
            float4 h4 = *(const float4*)(xs + tt * E + k);   // LDS broadcast
            a0 = fmaf(w[k],   h4.x, a0);
            a1 = fmaf(w[k+1], h4.y, a1);
            a2 = fmaf(w[k+2], h4.z, a2);
            a3 = fmaf(w[k+3], h4.w, a3);
        }
        psum[tid] = (a0 + a1) + (a2 + a3);
        __syncthreads();
        if (tid < 256)
            outb[(size_t)tt * G] = bias +
                ((psum[idx] + psum[idx + 256]) + (psum[idx + 512] + psum[idx + 768]));
        __syncthreads();                          // psum reused next tt
    }
}

// ---------------------------------------------------------------- LSTM scan
__global__ __launch_bounds__(1024, 4) void lstm_scan_l2(
    const float* __restrict__ xg,                 // [2][S][G]
    const float* __restrict__ Whh_f,
    const float* __restrict__ Whh_b,
    float* __restrict__ out,                      // [S][512]
    unsigned long long* __restrict__ fslot,       // [2][2][4][64] L2-RMW slots
    unsigned long long* __restrict__ sslot,       // [2][2][4][64] LLC slots
    unsigned long long* __restrict__ hs,
    int* __restrict__ ctl)
{
    __shared__ int s_role, s_fast;
    const int tid = threadIdx.x;

    if (tid == 0) {
        int xcc = get_xcc_id();
        int ticket = __hip_atomic_fetch_add(&ctl[xcc], 1,
                         __ATOMIC_RELAXED, __HIP_MEMORY_SCOPE_AGENT);
        if (ticket == 7) {
            int expv = -1;
            __hip_atomic_compare_exchange_strong(&ctl[16], &expv, xcc,
                __ATOMIC_RELAXED, __ATOMIC_RELAXED, __HIP_MEMORY_SCOPE_AGENT);
        }
        int wn;                                   // guaranteed (pigeonhole 64/8)
        do { wn = __hip_atomic_load(&ctl[16], __ATOMIC_RELAXED,
                                    __HIP_MEMORY_SCOPE_AGENT); } while (wn == -1);
        int role = (wn == xcc && ticket < 8) ? ticket : -1;
        int fast = 0;
        if (role >= 0) {
            // handshake: the exact main-loop RMW pair, bounded spins
            __hip_atomic_exchange(&hs[role], HSMAGIC + (unsigned)role,
                __ATOMIC_RELAXED, __HIP_MEMORY_SCOPE_WORKGROUP);
            int ok = 1;
            for (int p = 0; p < 8; ++p) {
                if (p == role) continue;
                unsigned long long v = 0; int spins = 0;
                do {
                    v = __hip_atomic_fetch_add(&hs[p], 0ull,
                            __ATOMIC_RELAXED, __HIP_MEMORY_SCOPE_WORKGROUP);
                } while (v != HSMAGIC + (unsigned)p && ++spins < (1 << 13));
                if (v != HSMAGIC + (unsigned)p) { ok = 0; break; }
            }
            // single-word arrival+vote: low byte = arrivals, byte1 = ok votes
            __hip_atomic_fetch_add(&ctl[17], 1 | (ok << 8),
                                   __ATOMIC_RELAXED, __HIP_MEMORY_SCOPE_AGENT);
            int vv;                               // guaranteed: all 8 add
            do { vv = __hip_atomic_load(&ctl[17], __ATOMIC_RELAXED,
                                        __HIP_MEMORY_SCOPE_AGENT);
            } while ((vv & 0xFF) < 8);
            fast = ((vv >> 8) & 0xFF) == 8;       // unanimous or slow
        }
        s_role = role; s_fast = fast;
    }
    __syncthreads();
    const int role = s_role;
    const int vote_fast = s_fast;
    if (role < 0) return;                         // not a worker
    const int b   = role & 3;
    const int dir = role >> 2;

    const int q    = tid >> 8;
    const int idx  = tid & 255;
    const int gate = idx & 3;
    const int hloc = idx >> 2;
    const int row  = gate * Hh + b * 64 + hloc;
    const float* W   = dir ? Whh_b : Whh_f;
    const float* xgd = xg + (size_t)dir * S * G;

    float w[64];
    #pragma unroll
    for (int k = 0; k < 64; k += 4) {
        float4 v = *(const float4*)(W + (size_t)row * Hh + q * 64 + k);
        w[k] = v.x; w[k+1] = v.y; w[k+2] = v.z; w[k+3] = v.w;
    }

    __shared__ __align__(16) float h_lds[Hh];
    __shared__ float psum[1024];
    if (tid < Hh) h_lds[tid] = 0.f;
    float c = 0.f;

    const bool isPoll = (tid >= 256 && tid < 448);
    const int pl   = tid - 256;
    const int pi   = pl >> 6;                     // 0..2
    const int word = pl & 63;
    const int pb   = pi + (pi >= b);              // peer block id
    int myfast = vote_fast;                       // per-thread sticky mode

    const int t0 = dir ? (S - 1) : 0;
    const int dt = dir ? -1 : 1;
    float xg_c = 0.f, xg_n1 = 0.f;                // 2-deep prefetch
    if (tid < 256) {
        xg_c  = xgd[(size_t)t0 * G + row];
        xg_n1 = xgd[(size_t)(t0 + dt) * G + row];
    }
    __syncthreads();

    for (int s = 0; s < S; ++s) {
        const int t = t0 + dt * s;
        float xg_n2 = 0.f;
        if (tid < 256 && s + 2 < S) xg_n2 = xgd[(size_t)(t + 2 * dt) * G + row];

        // partial matvec over this thread's k-quarter (wave-uniform LDS bcast)
        const float* hh = (const float*)h_lds + q * 64;
        float a0 = 0.f, a1 = 0.f, a2 = 0.f, a3 = 0.f;
        #pragma unroll
        for (int k = 0; k < 64; k += 4) {
            float4 h4 = *(const float4*)(hh + k);
            a0 = fmaf(w[k],   h4.x, a0);
            a1 = fmaf(w[k+1], h4.y, a1);
            a2 = fmaf(w[k+2], h4.z, a2);
            a3 = fmaf(w[k+3], h4.w, a3);
        }
        psum[tid] = (a0 + a1) + (a2 + a3);
        __syncthreads();                                     // B1: partials ready

        const unsigned st = (unsigned)(s + 1);
        const int base = ((dir << 1) | (s & 1)) << 8;        // slot group (256 u64)

        if (tid < 256) {
            float acc = xg_c +
                ((psum[idx] + psum[idx + 256]) + (psum[idx + 512] + psum[idx + 768]));
            float a = (gate == 2) ? tanhf(acc) : 1.f / (1.f + expf(-acc));
            float fv = __shfl_down(a, 1);
            float gv = __shfl_down(a, 2);
            float ov = __shfl_down(a, 3);
            if (gate == 0) {                                 // cell lane (i-gate)
                c = fv * c + a * gv;
                float h = ov * tanhf(c);
                unsigned long long pw = ((unsigned long long)st << 32) |
                                        (unsigned long long)__float_as_uint(h);
                // dual publish: L2 slot (fast consumers) + LLC slot (fallback)
                if (vote_fast)
                    __hip_atomic_exchange(&fslot[base + b * 64 + hloc], pw,
                        __ATOMIC_RELAXED, __HIP_MEMORY_SCOPE_WORKGROUP);
                __hip_atomic_store(&sslot[base + b * 64 + hloc], pw,
                    __ATOMIC_RELAXED, __HIP_MEMORY_SCOPE_AGENT);
                out[(size_t)t * 512 + dir * Hh + b * 64 + hloc] = h;
                h_lds[b * 64 + hloc] = h;
            }
        } else if (isPoll && s + 1 < S) {
            // poll peer pb's word for h(s) -- concurrent with producer tail
            unsigned long long v = 0; bool got = false;
            if (myfast) {
                unsigned long long* fp = &fslot[base + pb * 64 + word];
                #pragma unroll 1
                for (int it = 0; it < 256; ++it) {           // bounded fast poll
                    v = __hip_atomic_fetch_add(fp, 0ull,
                            __ATOMIC_RELAXED, __HIP_MEMORY_SCOPE_WORKGROUP);
                    if ((unsigned)(v >> 32) == st) { got = true; break; }
                }
                if (!got) myfast = 0;                        // sticky downgrade
            }
            if (!got) {                                      // proven LLC path
                unsigned long long* sp = &sslot[base + pb * 64 + word];
                do {
                    v = __hip_atomic_load(sp, __ATOMIC_RELAXED,
                                          __HIP_MEMORY_SCOPE_AGENT);
                } while ((unsigned)(v >> 32) != st);
            }
            h_lds[pb * 64 + word] = __uint_as_float((unsigned)v);
        }
        __syncthreads();                                     // B2: h(t) in LDS
        xg_c = xg_n1; xg_n1 = xg_n2;
    }
}

// ---------------------------------------------------------------- emissions
__global__ __launch_bounds__(256) void emissions_kernel(
    const float* __restrict__ lo,                 // [S][512]
    const float* __restrict__ Wout,               // [NT][512]
    const float* __restrict__ bout,
    float* __restrict__ em)                       // [S][NT]
{
    int gid = blockIdx.x * blockDim.x + threadIdx.x;
    if (gid >= S * NT) return;
    int t = gid / NT;
    int j = gid - t * NT;
    const float* x = lo + (size_t)t * 512;
    const float* w = Wout + (size_t)j * 512;
    float a0 = 0.f, a1 = 0.f, a2 = 0.f, a3 = 0.f;
    #pragma unroll 8
    for (int k = 0; k < 512; k += 4) {
        float4 xv = *(const float4*)(x + k);
        float4 wv = *(const float4*)(w + k);
        a0 = fmaf(xv.x, wv.x, a0);
        a1 = fmaf(xv.y, wv.y, a1);
        a2 = fmaf(xv.z, wv.z, a2);
        a3 = fmaf(xv.w, wv.w, a3);
    }
    em[gid] = bout[j] + ((a0 + a1) + (a2 + a3));
}

// ---------------------------------------------------------------- viterbi forward
// 64 lanes: lane = g*20 + j (g=0..2 active, lanes 60..63 spectators).
__global__ __launch_bounds__(64) void viterbi_fwd(
    const float* __restrict__ em,                 // [S][NT]
    const float* __restrict__ start_trans,
    const float* __restrict__ end_trans,
    const float* __restrict__ trans,              // [NT][NT] (from,to)
    unsigned char* __restrict__ bp,               // [S][NT]
    int* __restrict__ last_out)
{
    const int lane = threadIdx.x;
    const int g    = lane / 20;                   // 0,1,2 (3 = spectator)
    const int j    = lane - g * 20;               // to-tag (0..19 for g<3)
    const int i0   = g * 7;

    float tc[7];
    #pragma unroll
    for (int u = 0; u < 7; ++u) {
        int i = i0 + u;
        tc[u] = (g < 3 && i < 20) ? trans[i * NT + j] : -3.0e38f;
    }

    const int jj = (g < 3) ? j : 0;               // safe index for spectators
    float snew  = start_trans[jj] + em[jj];       // score(0)
    if (g == 0) bp[j] = (unsigned char)j;         // t=0: identity (never used)
    float e_cur = em[NT + jj];

    for (int t = 1; t < S; ++t) {
        float s_sub[7];
        #pragma unroll
        for (int u = 0; u < 7; ++u)
            s_sub[u] = __shfl(snew, i0 + u);      // sources are lanes 0..27
        float e_nxt = (t + 1 < S) ? em[(size_t)(t + 1) * NT + jj] : 0.f;

        float bv = s_sub[0] + tc[0];
        int   bi = i0;
        #pragma unroll
        for (int u = 1; u < 7; ++u) {
            float v = s_sub[u] + tc[u];
            if (v > bv) { bv = v; bi = i0 + u; }  // strict >: first-index in group
        }
        float v0 = __shfl(bv, jj), v1 = __shfl(bv, jj + 20), v2 = __shfl(bv, jj + 40);
        int   c0 = __shfl(bi, jj), c1 = __shfl(bi, jj + 20), c2 = __shfl(bi, jj + 40);
        float best = v0; int bidx = c0;
        if (v1 > best) { best = v1; bidx = c1; }
        if (v2 > best) { best = v2; bidx = c2; }
        snew = best + e_cur;
        if (g == 0) bp[(size_t)t * NT + j] = (unsigned char)bidx;
        e_cur = e_nxt;
    }

    float bv = __shfl(snew, 0) + end_trans[0];
    int   bi = 0;
    #pragma unroll 1
    for (int i = 1; i < 20; ++i) {
        float v = __shfl(snew, i) + end_trans[i];
        if (v > bv) { bv = v; bi = i; }
    }
    if (lane == 0) *last_out = bi;
}

// ---------------------------------------------------------------- backtrace
__global__ __launch_bounds__(64) void bt_maps(
    const unsigned char* __restrict__ bp, unsigned char* __restrict__ maps)
{
    __shared__ unsigned char lbp[CLEN * NT];
    const int c = blockIdx.x, tid = threadIdx.x;
    const unsigned* src = (const unsigned*)(bp + (size_t)c * CLEN * NT);
    unsigned* dst = (unsigned*)lbp;
    for (int q = tid; q < CLEN * NT / 4; q += 64) dst[q] = src[q];
    __syncthreads();
    if (tid < NT) {
        int x = tid;
        for (int t = CLEN - 1; t >= 0; --t) x = lbp[t * NT + x];
        maps[c * NT + tid] = (unsigned char)x;
    }
}

__global__ __launch_bounds__(64) void bt_boundary(
    const unsigned char* __restrict__ maps, const int* __restrict__ last_out,
    int* __restrict__ btags)
{
    __shared__ unsigned char m[NCHUNK * NT];
    const int tid = threadIdx.x;
    for (int q = tid; q < NCHUNK * NT; q += 64) m[q] = maps[q];
    __syncthreads();
    if (tid == 0) {
        int x = *last_out;
        btags[NCHUNK - 1] = x;
        for (int c = NCHUNK - 1; c >= 1; --c) {
            x = m[c * NT + x];
            btags[c - 1] = x;
        }
    }
}

__global__ __launch_bounds__(64) void bt_emit(
    const unsigned char* __restrict__ bp, const int* __restrict__ btags,
    int* __restrict__ path)
{
    __shared__ unsigned char lbp[CLEN * NT];
    const int c = blockIdx.x, tid = threadIdx.x;
    const unsigned* src = (const unsigned*)(bp + (size_t)c * CLEN * NT);
    unsigned* dst = (unsigned*)lbp;
    for (int q = tid; q < CLEN * NT / 4; q += 64) dst[q] = src[q];
    __syncthreads();
    if (tid == 0) {
        int x = btags[c];
        path[c * CLEN + CLEN - 1] = x;
        for (int t = CLEN - 1; t >= 1; --t) {
            x = lbp[t * NT + x];
            path[c * CLEN + t - 1] = x;
        }
    }
}

// ---------------------------------------------------------------- launcher
extern "C" void kernel_launch(void* const* d_in, const int* in_sizes, int n_in,
                              void* d_out, int out_size, void* d_ws, size_t ws_size,
                              hipStream_t stream) {
    const int*   sent   = (const int*)  d_in[0];
    const float* embed  = (const float*)d_in[1];
    const float* Wih_f  = (const float*)d_in[2];
    const float* Whh_f  = (const float*)d_in[3];
    const float* bih_f  = (const float*)d_in[4];
    const float* bhh_f  = (const float*)d_in[5];
    const float* Wih_b  = (const float*)d_in[6];
    const float* Whh_b  = (const float*)d_in[7];
    const float* bih_b  = (const float*)d_in[8];
    const float* bhh_b  = (const float*)d_in[9];
    const float* Wout   = (const float*)d_in[10];
    const float* bout   = (const float*)d_in[11];
    const float* start_trans = (const float*)d_in[12];
    const float* end_trans   = (const float*)d_in[13];
    const float* trans       = (const float*)d_in[14];
    int* path = (int*)d_out;

    char* ws = (char*)d_ws;
    size_t off = 0;
    float* xg = (float*)(ws + off); off += (size_t)2 * S * G * 4;   // 64 MB
    float* lo = (float*)(ws + off); off += (size_t)S * 512 * 4;     // 16 MB
    float* em = (float*)(ws + off); off += (size_t)S * NT * 4;      // 640 KB
    unsigned char* bp   = (unsigned char*)(ws + off); off += (size_t)S * NT;  // 160 KB
    unsigned char* maps = (unsigned char*)(ws + off); off += 4096;
    int* btags = (int*)(ws + off); off += 1024;
    int* lastp = (int*)(ws + off); off += 256;
    off = (off + 255) & ~(size_t)255;
    unsigned long long* fslot = (unsigned long long*)(ws + off); off += 1024 * 8;
    unsigned long long* sslot = (unsigned long long*)(ws + off); off += 1024 * 8;
    unsigned long long* hs    = (unsigned long long*)(ws + off); off += 8 * 8;
    int* ctl = (int*)(ws + off); off += 256;

    init_sync<<<dim3(1), 1024, 0, stream>>>(fslot, sslot, hs, ctl);
    xg_project<<<dim3(S / 32, 4, 2), 1024, 0, stream>>>(
        sent, embed, Wih_f, bih_f, bhh_f, Wih_b, bih_b, bhh_b, xg);
    lstm_scan_l2<<<dim3(NCAND), 1024, 0, stream>>>(xg, Whh_f, Whh_b, lo,
                                                   fslot, sslot, hs, ctl);
    emissions_kernel<<<dim3((S * NT + 255) / 256), 256, 0, stream>>>(lo, Wout, bout, em);
    viterbi_fwd<<<dim3(1), 64, 0, stream>>>(em, start_trans, end_trans, trans, bp, lastp);
    bt_maps<<<dim3(NCHUNK), 64, 0, stream>>>(bp, maps);
    bt_boundary<<<dim3(1), 64, 0, stream>>>(maps, lastp, btags);
    bt_emit<<<dim3(NCHUNK), 64, 0, stream>>>(bp, btags, path);
}